// Round 1
// baseline (3663.160 us; speedup 1.0000x reference)
//
#include <hip/hip_runtime.h>

// Problem constants (fixed by reference)
constexpr int BATCH = 256;
constexpr int TSTEPS = 250;
constexpr int NI = 700;
constexpr int NH = 512;
constexpr int NO = 20;

#define B_J0  0.01f
#define BETA_ 1.8f

// ---------------------------------------------------------------------------
// Tiled transpose with optional mask fused:  out[c*R + r] = in[r*C + c] * mask[c*R + r]
// in is [R][C], out is [C][R]. mask (if non-null) is indexed by the OUTPUT offset,
// which matches W_h11e^T[j,h] = W_h11[h,j] * mask[j,h].
__global__ void transpose_mask(const float* __restrict__ in, const float* __restrict__ mask,
                               float* __restrict__ out, int R, int C) {
    __shared__ float tile[32][33];
    int cb = blockIdx.x * 32, rb = blockIdx.y * 32;
    int tx = threadIdx.x, ty = threadIdx.y;   // block (32,8)
    #pragma unroll
    for (int i = 0; i < 32; i += 8) {
        int r = rb + ty + i, c = cb + tx;
        if (r < R && c < C) tile[ty + i][tx] = in[(size_t)r * C + c];
    }
    __syncthreads();
    #pragma unroll
    for (int i = 0; i < 32; i += 8) {
        int c = cb + ty + i, r = rb + tx;
        if (c < C && r < R) {
            float v = tile[tx][ty + i];
            if (mask) v *= mask[(size_t)c * R + r];
            out[(size_t)c * R + r] = v;
        }
    }
}

// W_out [NO][NH] -> W_outT [NH][NO]  (tiny: 10240 elems)
__global__ void transpose_wout(const float* __restrict__ in, float* __restrict__ out) {
    int idx = blockIdx.x * blockDim.x + threadIdx.x;
    if (idx < NH * NO) {
        int j = idx / NO, o = idx % NO;
        out[idx] = in[o * NH + j];
    }
}

// A_norm = sum |W_h11 * mask0^T| + |W_h22 * mask1^T| — single block, deterministic tree reduce
__global__ void anorm_kernel(const float* __restrict__ Wh11, const float* __restrict__ Wh22,
                             const float* __restrict__ mask, float* __restrict__ out) {
    __shared__ float red[1024];
    int tid = threadIdx.x;
    float s = 0.f;
    for (int idx = tid; idx < NH * NH; idx += 1024) {
        int h = idx / NH, j = idx % NH;
        s += fabsf(Wh11[idx] * mask[j * NH + h]);
        s += fabsf(Wh22[idx] * mask[NH * NH + j * NH + h]);
    }
    red[tid] = s;
    __syncthreads();
    for (int st = 512; st > 0; st >>= 1) {
        if (tid < st) red[tid] += red[tid + st];
        __syncthreads();
    }
    if (tid == 0) out[0] = red[0];
}

// Deterministic, order-preserving block-wide stream compaction (block = 512 = 8 waves).
// Appends `idx` of threads with flag=true to list starting at `base`, in tid order.
// Returns the new total count (uniform across the block). Contains 2 barriers.
__device__ __forceinline__ int block_compact(bool flag, int idx, int* list, int base,
                                             int* waveCnt, int tid) {
    unsigned long long m = __ballot(flag ? 1 : 0);
    int lane = tid & 63, w = tid >> 6;
    if (lane == 0) waveCnt[w] = __popcll(m);
    __syncthreads();
    int off = base;
    for (int i = 0; i < w; ++i) off += waveCnt[i];
    if (flag) list[off + __popcll(m & ((1ull << lane) - 1ull))] = idx;
    int tot = base;
    #pragma unroll
    for (int i = 0; i < 8; ++i) tot += waveCnt[i];
    __syncthreads();   // list fully written; waveCnt free for reuse
    return tot;
}

// ---------------------------------------------------------------------------
// Main kernel: one block per batch sample, 512 threads = 512 neurons, full T loop.
__global__ __launch_bounds__(512) void snn_kernel(
    const float* __restrict__ input,
    const float* __restrict__ h1m0, const float* __restrict__ h2m0, const float* __restrict__ om0,
    const float* __restrict__ b_in, const float* __restrict__ b_h11,
    const float* __restrict__ b_h12, const float* __restrict__ b_h22,
    const float* __restrict__ b_o,
    const float* __restrict__ tau_adp_h1, const float* __restrict__ tau_adp_h2,
    const float* __restrict__ tau_m_h1, const float* __restrict__ tau_m_h2,
    const float* __restrict__ tau_m_o,
    const float* __restrict__ WinT, const float* __restrict__ Wh11T,
    const float* __restrict__ Wh12T, const float* __restrict__ Wh22T,
    const float* __restrict__ WoutT,
    float* __restrict__ out)
{
    __shared__ int actIn[NI];
    __shared__ int actS1[NH];
    __shared__ int actS2[NH];
    __shared__ int waveCnt[8];
    __shared__ float part[320];
    __shared__ float smx[NO];
    __shared__ float se[NO];

    const int tid = threadIdx.x;
    const int b = blockIdx.x;
    const int h = tid;

    float mem1 = h1m0[b * NH + h];
    float mem2 = h2m0[b * NH + h];
    float spk1 = 0.f, spk2 = 0.f, s1c = 0.f, s2c = 0.f;
    const float al1 = expf(-1.f / tau_m_h1[h]);
    const float al2 = expf(-1.f / tau_m_h2[h]);
    const float ro1 = expf(-1.f / tau_adp_h1[h]);
    const float ro2 = expf(-1.f / tau_adp_h2[h]);
    const float bs1 = b_in[h] + b_h11[h];
    const float bs2 = b_h12[h] + b_h22[h];

    float outm = 0.f, accO = 0.f, alo = 0.f, bo = 0.f;
    if (tid < NO) {
        outm = om0[b * NO + tid];
        alo = expf(-1.f / tau_m_o[tid]);
        bo = b_o[tid];
    }

    int nS1 = 0, nS2 = 0;
    const float* xbase = input + (size_t)b * TSTEPS * NI;

    for (int t = 0; t < TSTEPS; ++t) {
        const float* xr = xbase + (size_t)t * NI;
        // ---- build active input list (700 = 512 + 188), index order preserved
        float x0 = xr[tid];
        bool f1v = tid < (NI - NH);
        float x1 = f1v ? xr[NH + tid] : 0.f;
        int nIn = block_compact(x0 > 0.f, tid, actIn, 0, waveCnt, tid);
        nIn = block_compact(f1v && (x1 > 0.f), NH + tid, actIn, nIn, waveCnt, tid);

        // ---- layer 1: i1 = sum_{active in} WinT + sum_{active spk1 old} Wh11T + biases
        float a0 = 0.f, a1 = 0.f, a2 = 0.f, a3 = 0.f;
        int k = 0;
        for (; k + 3 < nIn; k += 4) {
            a0 += WinT[actIn[k] * NH + h];
            a1 += WinT[actIn[k + 1] * NH + h];
            a2 += WinT[actIn[k + 2] * NH + h];
            a3 += WinT[actIn[k + 3] * NH + h];
        }
        for (; k < nIn; ++k) a0 += WinT[actIn[k] * NH + h];
        for (k = 0; k + 3 < nS1; k += 4) {
            a0 += Wh11T[actS1[k] * NH + h];
            a1 += Wh11T[actS1[k + 1] * NH + h];
            a2 += Wh11T[actS1[k + 2] * NH + h];
            a3 += Wh11T[actS1[k + 3] * NH + h];
        }
        for (; k < nS1; ++k) a0 += Wh11T[actS1[k] * NH + h];
        float i1 = ((a0 + a1) + (a2 + a3)) + bs1;

        float b1 = ro1 * B_J0 + (1.f - ro1) * spk1;
        float B1 = B_J0 + BETA_ * b1;
        mem1 = mem1 * al1 + (1.f - al1) * i1 - B1 * spk1;
        float ns1 = (mem1 - B1) > 0.f ? 1.f : 0.f;
        spk1 = ns1;
        s1c += ns1;
        nS1 = block_compact(ns1 != 0.f, tid, actS1, 0, waveCnt, tid);

        // ---- layer 2: i2 = sum_{active spk1 new} Wh12T + sum_{active spk2 old} Wh22T + biases
        a0 = a1 = a2 = a3 = 0.f;
        for (k = 0; k + 3 < nS1; k += 4) {
            a0 += Wh12T[actS1[k] * NH + h];
            a1 += Wh12T[actS1[k + 1] * NH + h];
            a2 += Wh12T[actS1[k + 2] * NH + h];
            a3 += Wh12T[actS1[k + 3] * NH + h];
        }
        for (; k < nS1; ++k) a0 += Wh12T[actS1[k] * NH + h];
        for (k = 0; k + 3 < nS2; k += 4) {
            a0 += Wh22T[actS2[k] * NH + h];
            a1 += Wh22T[actS2[k + 1] * NH + h];
            a2 += Wh22T[actS2[k + 2] * NH + h];
            a3 += Wh22T[actS2[k + 3] * NH + h];
        }
        for (; k < nS2; ++k) a0 += Wh22T[actS2[k] * NH + h];
        float i2 = ((a0 + a1) + (a2 + a3)) + bs2;

        float b2 = ro2 * B_J0 + (1.f - ro2) * spk2;
        float B2 = B_J0 + BETA_ * b2;
        mem2 = mem2 * al2 + (1.f - al2) * i2 - B2 * spk2;
        float ns2 = (mem2 - B2) > 0.f ? 1.f : 0.f;
        spk2 = ns2;
        s2c += ns2;
        nS2 = block_compact(ns2 != 0.f, tid, actS2, 0, waveCnt, tid);

        // ---- readout: io = spk2_new @ W_out^T + b_o, 16 k-slices x 20 outputs
        if (tid < 320) {
            int o = tid % NO, r = tid / NO;
            float p = 0.f;
            for (int kk = r; kk < nS2; kk += 16) p += WoutT[actS2[kk] * NO + o];
            part[tid] = p;
        }
        __syncthreads();
        float eo = 0.f;
        if (tid < NO) {
            float io = bo;
            #pragma unroll
            for (int r = 0; r < 16; ++r) io += part[r * NO + tid];
            outm = outm * alo + (1.f - alo) * io;
            smx[tid] = outm;
        }
        __syncthreads();
        if (tid < NO) {
            float mx = smx[0];
            #pragma unroll
            for (int j = 1; j < NO; ++j) mx = fmaxf(mx, smx[j]);
            eo = expf(outm - mx);
            se[tid] = eo;
        }
        __syncthreads();
        if (tid < NO) {
            float s = se[0];
            #pragma unroll
            for (int j = 1; j < NO; ++j) s += se[j];
            accO += eo / s;
        }
        __syncthreads();
    }

    // ---- epilogue
    if (tid < NO) out[b * NO + tid] = accO;
    out[BATCH * NO + (size_t)b * NH + h] = s1c * (1.f / TSTEPS);
    out[BATCH * NO + BATCH * NH + (size_t)b * NH + h] = s2c * (1.f / TSTEPS);
}

// ---------------------------------------------------------------------------
extern "C" void kernel_launch(void* const* d_in, const int* in_sizes, int n_in,
                              void* d_out, int out_size, void* d_ws, size_t ws_size,
                              hipStream_t stream) {
    const float* input      = (const float*)d_in[0];
    const float* mask       = (const float*)d_in[1];
    const float* h1m0       = (const float*)d_in[2];
    const float* h2m0       = (const float*)d_in[3];
    const float* om0        = (const float*)d_in[4];
    const float* W_in       = (const float*)d_in[5];
    const float* b_in       = (const float*)d_in[6];
    const float* W_h11      = (const float*)d_in[7];
    const float* b_h11      = (const float*)d_in[8];
    const float* W_h12      = (const float*)d_in[9];
    const float* b_h12      = (const float*)d_in[10];
    const float* W_h22      = (const float*)d_in[11];
    const float* b_h22      = (const float*)d_in[12];
    const float* W_out      = (const float*)d_in[13];
    const float* b_o        = (const float*)d_in[14];
    const float* tau_adp_h1 = (const float*)d_in[15];
    const float* tau_adp_h2 = (const float*)d_in[16];
    const float* tau_m_h1   = (const float*)d_in[17];
    const float* tau_m_h2   = (const float*)d_in[18];
    const float* tau_m_o    = (const float*)d_in[19];

    float* out = (float*)d_out;
    float* ws  = (float*)d_ws;

    float* WinT  = ws;                   // 700*512
    float* Wh11T = WinT + NI * NH;       // 512*512
    float* Wh12T = Wh11T + NH * NH;
    float* Wh22T = Wh12T + NH * NH;
    float* WoutT = Wh22T + NH * NH;      // 512*20

    dim3 tb(32, 8);
    transpose_mask<<<dim3((NI + 31) / 32, (NH + 31) / 32), tb, 0, stream>>>(W_in, nullptr, WinT, NH, NI);
    transpose_mask<<<dim3(16, 16), tb, 0, stream>>>(W_h11, mask,            Wh11T, NH, NH);
    transpose_mask<<<dim3(16, 16), tb, 0, stream>>>(W_h12, nullptr,         Wh12T, NH, NH);
    transpose_mask<<<dim3(16, 16), tb, 0, stream>>>(W_h22, mask + NH * NH,  Wh22T, NH, NH);
    transpose_wout<<<(NH * NO + 255) / 256, 256, 0, stream>>>(W_out, WoutT);
    anorm_kernel<<<1, 1024, 0, stream>>>(W_h11, W_h22, mask, out + BATCH * NO + 2 * BATCH * NH);

    snn_kernel<<<BATCH, NH, 0, stream>>>(input, h1m0, h2m0, om0,
        b_in, b_h11, b_h12, b_h22, b_o,
        tau_adp_h1, tau_adp_h2, tau_m_h1, tau_m_h2, tau_m_o,
        WinT, Wh11T, Wh12T, Wh22T, WoutT, out);
}

// Round 2
// 2038.908 us; speedup vs baseline: 1.7966x; 1.7966x over previous
//
#include <hip/hip_runtime.h>

// Problem constants (fixed by reference)
constexpr int BATCH = 256;
constexpr int TSTEPS = 250;
constexpr int NI = 700;
constexpr int NH = 512;
constexpr int NO = 20;

#define B_J0  0.01f
#define BETA_ 1.8f

// ---------------------------------------------------------------------------
// Tiled transpose with optional mask fused:  out[c*R + r] = in[r*C + c] * mask[c*R + r]
__global__ void transpose_mask(const float* __restrict__ in, const float* __restrict__ mask,
                               float* __restrict__ out, int R, int C) {
    __shared__ float tile[32][33];
    int cb = blockIdx.x * 32, rb = blockIdx.y * 32;
    int tx = threadIdx.x, ty = threadIdx.y;   // block (32,8)
    #pragma unroll
    for (int i = 0; i < 32; i += 8) {
        int r = rb + ty + i, c = cb + tx;
        if (r < R && c < C) tile[ty + i][tx] = in[(size_t)r * C + c];
    }
    __syncthreads();
    #pragma unroll
    for (int i = 0; i < 32; i += 8) {
        int c = cb + ty + i, r = rb + tx;
        if (c < C && r < R) {
            float v = tile[tx][ty + i];
            if (mask) v *= mask[(size_t)c * R + r];
            out[(size_t)c * R + r] = v;
        }
    }
}

__global__ void transpose_wout(const float* __restrict__ in, float* __restrict__ out) {
    int idx = blockIdx.x * blockDim.x + threadIdx.x;
    if (idx < NH * NO) {
        int j = idx / NO, o = idx % NO;
        out[idx] = in[o * NH + j];
    }
}

// A_norm: deterministic two-stage reduction (stage1: 128 blocks, stage2: 1 block)
__global__ void anorm_stage1(const float* __restrict__ Wh11, const float* __restrict__ Wh22,
                             const float* __restrict__ mask, float* __restrict__ partial) {
    __shared__ float red[256];
    int tid = threadIdx.x;
    float s = 0.f;
    for (int idx = blockIdx.x * 256 + tid; idx < NH * NH; idx += 256 * 128) {
        int hh = idx / NH, j = idx % NH;
        s += fabsf(Wh11[idx] * mask[j * NH + hh]);
        s += fabsf(Wh22[idx] * mask[NH * NH + j * NH + hh]);
    }
    red[tid] = s;
    __syncthreads();
    for (int st = 128; st > 0; st >>= 1) {
        if (tid < st) red[tid] += red[tid + st];
        __syncthreads();
    }
    if (tid == 0) partial[blockIdx.x] = red[0];
}

__global__ void anorm_stage2(const float* __restrict__ partial, float* __restrict__ out) {
    __shared__ float red[128];
    int tid = threadIdx.x;
    red[tid] = partial[tid];
    __syncthreads();
    for (int st = 64; st > 0; st >>= 1) {
        if (tid < st) red[tid] += red[tid + st];
        __syncthreads();
    }
    if (tid == 0) out[0] = red[0];
}

// Deterministic, order-preserving block-wide stream compaction (block = 512 = 8 waves).
__device__ __forceinline__ int block_compact(bool flag, int idx, int* list, int base,
                                             int* waveCnt, int tid) {
    unsigned long long m = __ballot(flag ? 1 : 0);
    int lane = tid & 63, w = tid >> 6;
    if (lane == 0) waveCnt[w] = __popcll(m);
    __syncthreads();
    int off = base;
    for (int i = 0; i < w; ++i) off += waveCnt[i];
    if (flag) list[off + __popcll(m & ((1ull << lane) - 1ull))] = idx;
    int tot = base;
    #pragma unroll
    for (int i = 0; i < 8; ++i) tot += waveCnt[i];
    __syncthreads();
    return tot;
}

__device__ __forceinline__ void f4add(float4& a, const float4 b) {
    a.x += b.x; a.y += b.y; a.z += b.z; a.w += b.w;
}

__device__ __forceinline__ float4 ld4(const float* __restrict__ W, int j, int q) {
    return *reinterpret_cast<const float4*>(W + ((size_t)j << 9) + (q << 2));
}

// Gather a slice [kb,ke) of active rows of W, 8 float4 accumulators for MLP.
__device__ __forceinline__ float4 gather_slice(const int* __restrict__ list, int kb, int ke,
                                               const float* __restrict__ W, int q) {
    float4 a0{0,0,0,0}, a1{0,0,0,0}, a2{0,0,0,0}, a3{0,0,0,0},
           a4{0,0,0,0}, a5{0,0,0,0}, a6{0,0,0,0}, a7{0,0,0,0};
    int k = kb;
    for (; k + 7 < ke; k += 8) {
        int j0 = list[k],     j1 = list[k + 1], j2 = list[k + 2], j3 = list[k + 3];
        int j4 = list[k + 4], j5 = list[k + 5], j6 = list[k + 6], j7 = list[k + 7];
        f4add(a0, ld4(W, j0, q)); f4add(a1, ld4(W, j1, q));
        f4add(a2, ld4(W, j2, q)); f4add(a3, ld4(W, j3, q));
        f4add(a4, ld4(W, j4, q)); f4add(a5, ld4(W, j5, q));
        f4add(a6, ld4(W, j6, q)); f4add(a7, ld4(W, j7, q));
    }
    for (; k < ke; ++k) f4add(a0, ld4(W, list[k], q));
    f4add(a0, a1); f4add(a2, a3); f4add(a4, a5); f4add(a6, a7);
    f4add(a0, a2); f4add(a4, a6); f4add(a0, a4);
    return a0;
}

// ---------------------------------------------------------------------------
// Main kernel: one block per batch sample, 512 threads, full T loop.
__global__ __launch_bounds__(512) void snn_kernel(
    const float* __restrict__ input,
    const float* __restrict__ h1m0, const float* __restrict__ h2m0, const float* __restrict__ om0,
    const float* __restrict__ b_in, const float* __restrict__ b_h11,
    const float* __restrict__ b_h12, const float* __restrict__ b_h22,
    const float* __restrict__ b_o,
    const float* __restrict__ tau_adp_h1, const float* __restrict__ tau_adp_h2,
    const float* __restrict__ tau_m_h1, const float* __restrict__ tau_m_h2,
    const float* __restrict__ tau_m_o,
    const float* __restrict__ WinT, const float* __restrict__ Wh11T,
    const float* __restrict__ Wh12T, const float* __restrict__ Wh22T,
    const float* __restrict__ WoutT,
    float* __restrict__ out)
{
    __shared__ int actIn[NI];
    __shared__ int actS1[NH];
    __shared__ int actS2[NH];
    __shared__ int waveCnt[8];
    __shared__ float4 part4[4 * 128];     // 4 slices x 128 float4 = 512 neurons
    __shared__ float part[320];
    __shared__ float smx[NO];
    __shared__ float se[NO];

    const int tid = threadIdx.x;
    const int b = blockIdx.x;
    const int h = tid;
    const int s = tid >> 7;       // k-slice 0..3
    const int q = tid & 127;      // float4 column group

    float mem1 = h1m0[b * NH + h];
    float mem2 = h2m0[b * NH + h];
    float spk1 = 0.f, spk2 = 0.f, s1c = 0.f, s2c = 0.f;
    const float al1 = expf(-1.f / tau_m_h1[h]);
    const float al2 = expf(-1.f / tau_m_h2[h]);
    const float ro1 = expf(-1.f / tau_adp_h1[h]);
    const float ro2 = expf(-1.f / tau_adp_h2[h]);
    const float bs1 = b_in[h] + b_h11[h];
    const float bs2 = b_h12[h] + b_h22[h];

    float outm = 0.f, accO = 0.f, alo = 0.f, bo = 0.f;
    if (tid < NO) {
        outm = om0[b * NO + tid];
        alo = expf(-1.f / tau_m_o[tid]);
        bo = b_o[tid];
    }

    int nS1 = 0, nS2 = 0;
    const float* xbase = input + (size_t)b * TSTEPS * NI;
    const bool f1v = tid < (NI - NH);

    // preload step-0 input (non-temporal: streamed once, don't evict weights)
    float x0 = __builtin_nontemporal_load(xbase + tid);
    float x1 = f1v ? __builtin_nontemporal_load(xbase + NH + tid) : 0.f;

    for (int t = 0; t < TSTEPS; ++t) {
        // ---- active input list (700 = 512 + 188), index order preserved
        bool f0 = x0 > 0.f;
        bool f1 = f1v && (x1 > 0.f);
        int nIn = block_compact(f0, tid, actIn, 0, waveCnt, tid);
        nIn = block_compact(f1, NH + tid, actIn, nIn, waveCnt, tid);

        // prefetch next step's input; latency hides under the gather below
        if (t + 1 < TSTEPS) {
            const float* xn = xbase + (size_t)(t + 1) * NI;
            x0 = __builtin_nontemporal_load(xn + tid);
            x1 = f1v ? __builtin_nontemporal_load(xn + NH + tid) : 0.f;
        }

        // ---- layer 1 gather: slice s of {active inputs -> WinT} + {active spk1 -> Wh11T}
        {
            float4 p = gather_slice(actIn, (nIn * s) >> 2, (nIn * (s + 1)) >> 2, WinT, q);
            float4 p2 = gather_slice(actS1, (nS1 * s) >> 2, (nS1 * (s + 1)) >> 2, Wh11T, q);
            f4add(p, p2);
            part4[(s << 7) + q] = p;
        }
        __syncthreads();
        const float* pf = (const float*)part4;
        float i1 = ((pf[h] + pf[NH + h]) + (pf[2 * NH + h] + pf[3 * NH + h])) + bs1;

        float b1 = ro1 * B_J0 + (1.f - ro1) * spk1;
        float B1 = B_J0 + BETA_ * b1;
        mem1 = mem1 * al1 + (1.f - al1) * i1 - B1 * spk1;
        float ns1 = (mem1 - B1) > 0.f ? 1.f : 0.f;
        spk1 = ns1;
        s1c += ns1;
        nS1 = block_compact(ns1 != 0.f, tid, actS1, 0, waveCnt, tid);

        // ---- layer 2 gather: {new spk1 -> Wh12T} + {old spk2 -> Wh22T}
        {
            float4 p = gather_slice(actS1, (nS1 * s) >> 2, (nS1 * (s + 1)) >> 2, Wh12T, q);
            float4 p2 = gather_slice(actS2, (nS2 * s) >> 2, (nS2 * (s + 1)) >> 2, Wh22T, q);
            f4add(p, p2);
            part4[(s << 7) + q] = p;
        }
        __syncthreads();
        float i2 = ((pf[h] + pf[NH + h]) + (pf[2 * NH + h] + pf[3 * NH + h])) + bs2;

        float b2 = ro2 * B_J0 + (1.f - ro2) * spk2;
        float B2 = B_J0 + BETA_ * b2;
        mem2 = mem2 * al2 + (1.f - al2) * i2 - B2 * spk2;
        float ns2 = (mem2 - B2) > 0.f ? 1.f : 0.f;
        spk2 = ns2;
        s2c += ns2;
        nS2 = block_compact(ns2 != 0.f, tid, actS2, 0, waveCnt, tid);

        // ---- readout: io = spk2_new @ W_out^T + b_o, 16 k-slices x 20 outputs
        if (tid < 320) {
            int o = tid % NO, r = tid / NO;
            float p = 0.f;
            for (int kk = r; kk < nS2; kk += 16) p += WoutT[actS2[kk] * NO + o];
            part[tid] = p;
        }
        __syncthreads();
        float eo = 0.f;
        if (tid < NO) {
            float io = bo;
            #pragma unroll
            for (int r = 0; r < 16; ++r) io += part[r * NO + tid];
            outm = outm * alo + (1.f - alo) * io;
            smx[tid] = outm;
        }
        __syncthreads();
        if (tid < NO) {
            float mx = smx[0];
            #pragma unroll
            for (int j = 1; j < NO; ++j) mx = fmaxf(mx, smx[j]);
            eo = expf(outm - mx);
            se[tid] = eo;
        }
        __syncthreads();
        if (tid < NO) {
            float ssum = se[0];
            #pragma unroll
            for (int j = 1; j < NO; ++j) ssum += se[j];
            accO += eo / ssum;
        }
        __syncthreads();
    }

    // ---- epilogue
    if (tid < NO) out[b * NO + tid] = accO;
    out[BATCH * NO + (size_t)b * NH + h] = s1c * (1.f / TSTEPS);
    out[BATCH * NO + BATCH * NH + (size_t)b * NH + h] = s2c * (1.f / TSTEPS);
}

// ---------------------------------------------------------------------------
extern "C" void kernel_launch(void* const* d_in, const int* in_sizes, int n_in,
                              void* d_out, int out_size, void* d_ws, size_t ws_size,
                              hipStream_t stream) {
    const float* input      = (const float*)d_in[0];
    const float* mask       = (const float*)d_in[1];
    const float* h1m0       = (const float*)d_in[2];
    const float* h2m0       = (const float*)d_in[3];
    const float* om0        = (const float*)d_in[4];
    const float* W_in       = (const float*)d_in[5];
    const float* b_in       = (const float*)d_in[6];
    const float* W_h11      = (const float*)d_in[7];
    const float* b_h11      = (const float*)d_in[8];
    const float* W_h12      = (const float*)d_in[9];
    const float* b_h12      = (const float*)d_in[10];
    const float* W_h22      = (const float*)d_in[11];
    const float* b_h22      = (const float*)d_in[12];
    const float* W_out      = (const float*)d_in[13];
    const float* b_o        = (const float*)d_in[14];
    const float* tau_adp_h1 = (const float*)d_in[15];
    const float* tau_adp_h2 = (const float*)d_in[16];
    const float* tau_m_h1   = (const float*)d_in[17];
    const float* tau_m_h2   = (const float*)d_in[18];
    const float* tau_m_o    = (const float*)d_in[19];

    float* out = (float*)d_out;
    float* ws  = (float*)d_ws;

    float* WinT  = ws;                   // 700*512
    float* Wh11T = WinT + NI * NH;       // 512*512
    float* Wh12T = Wh11T + NH * NH;
    float* Wh22T = Wh12T + NH * NH;
    float* WoutT = Wh22T + NH * NH;      // 512*20
    float* apart = WoutT + NH * NO;      // 128 partials for anorm

    dim3 tb(32, 8);
    transpose_mask<<<dim3((NI + 31) / 32, (NH + 31) / 32), tb, 0, stream>>>(W_in, nullptr, WinT, NH, NI);
    transpose_mask<<<dim3(16, 16), tb, 0, stream>>>(W_h11, mask,            Wh11T, NH, NH);
    transpose_mask<<<dim3(16, 16), tb, 0, stream>>>(W_h12, nullptr,         Wh12T, NH, NH);
    transpose_mask<<<dim3(16, 16), tb, 0, stream>>>(W_h22, mask + NH * NH,  Wh22T, NH, NH);
    transpose_wout<<<(NH * NO + 255) / 256, 256, 0, stream>>>(W_out, WoutT);
    anorm_stage1<<<128, 256, 0, stream>>>(W_h11, W_h22, mask, apart);
    anorm_stage2<<<1, 128, 0, stream>>>(apart, out + BATCH * NO + 2 * BATCH * NH);

    snn_kernel<<<BATCH, NH, 0, stream>>>(input, h1m0, h2m0, om0,
        b_in, b_h11, b_h12, b_h22, b_o,
        tau_adp_h1, tau_adp_h2, tau_m_h1, tau_m_h2, tau_m_o,
        WinT, Wh11T, Wh12T, Wh22T, WoutT, out);
}